// Round 3
// baseline (2662.874 us; speedup 1.0000x reference)
//
#include <hip/hip_runtime.h>
#include <hip/hip_bf16.h>

#define SEQ   2048
#define DIM   4096
#define NH    32
#define NKV   8
#define HD    128
#define KVDIM 1024
#define SCALE 0.08838834764831845f

typedef __attribute__((ext_vector_type(8))) short bf16x8;
typedef __attribute__((ext_vector_type(4))) float f32x4;

__device__ __forceinline__ float bfhi(uint u) {  // high ushort -> float
  union { uint i; float f; } v; v.i = u & 0xffff0000u; return v.f;
}
__device__ __forceinline__ float bflo(uint u) {  // low ushort -> float
  union { uint i; float f; } v; v.i = u << 16; return v.f;
}
__device__ __forceinline__ ushort f2bf(float f) {  // RTN fp32 -> bf16 bits
  __hip_bfloat16 h = __float2bfloat16(f);
  return *reinterpret_cast<ushort*>(&h);
}

// ---------------- GEMM tiles: 128x128, BK=32, 4 waves (2x2), 16 MFMA/iter -----
#define BM 128
#define BN 128
#define BKT 32
#define AS_STRIDE 40    // ushorts; 80B rows -> 16B-aligned b128 LDS ops
#define BS_STRIDE 130   // ushorts; 260B rows -> odd rows 4B-aligned: stage with
                        // 4B stores only (never uint2/uint4 -> ds_write_b64 UB)

// ---- Variant 1: A fp32, B fp32 -> C bf16 (the Q/K/V projections) -------------
__global__ __launch_bounds__(256) void gemm_f32f32_bf16(
    const float* __restrict__ A, const float* __restrict__ B,
    ushort* __restrict__ C, int M, int N, int K)
{
  __shared__ __align__(16) ushort As[BM * AS_STRIDE];
  __shared__ __align__(16) ushort Bs[BKT * BS_STRIDE];

  const int tid  = threadIdx.x;
  const int lane = tid & 63;
  const int wave = tid >> 6;
  const int wr = wave >> 1, wc = wave & 1;
  const int m0 = blockIdx.y * BM;
  const int n0 = blockIdx.x * BN;
  const int quad = lane >> 4;
  const int l16  = lane & 15;

  f32x4 acc[4][4];
#pragma unroll
  for (int bm = 0; bm < 4; ++bm)
#pragma unroll
    for (int bn = 0; bn < 4; ++bn)
      acc[bm][bn] = (f32x4){0.f, 0.f, 0.f, 0.f};

  for (int k0 = 0; k0 < K; k0 += BKT) {
    // stage A tile 128x32: 8 fp32/thread -> bf16
#pragma unroll
    for (int c = 0; c < 2; ++c) {
      int id = tid + c * 256;
      int row = id >> 2, colg = (id & 3) << 3;
      const float* src = A + (size_t)(m0 + row) * K + k0 + colg;
      float4 v0 = *(const float4*)src;
      float4 v1 = *(const float4*)(src + 4);
      ushort* dst = &As[row * AS_STRIDE + colg];   // 16B-aligned
      dst[0] = f2bf(v0.x); dst[1] = f2bf(v0.y);
      dst[2] = f2bf(v0.z); dst[3] = f2bf(v0.w);
      dst[4] = f2bf(v1.x); dst[5] = f2bf(v1.y);
      dst[6] = f2bf(v1.z); dst[7] = f2bf(v1.w);
    }
    // stage B tile 32x128: 8 fp32/thread -> bf16, 4B LDS stores
#pragma unroll
    for (int c = 0; c < 2; ++c) {
      int id = tid + c * 256;
      int row = id >> 4, colg = (id & 15) << 3;
      const float* src = B + (size_t)(k0 + row) * N + n0 + colg;
      float4 v0 = *(const float4*)src;
      float4 v1 = *(const float4*)(src + 4);
      uint* dst = (uint*)(&Bs[row * BS_STRIDE + colg]);  // byte off ≡ 0 mod 4
      dst[0] = (uint)f2bf(v0.x) | ((uint)f2bf(v0.y) << 16);
      dst[1] = (uint)f2bf(v0.z) | ((uint)f2bf(v0.w) << 16);
      dst[2] = (uint)f2bf(v1.x) | ((uint)f2bf(v1.y) << 16);
      dst[3] = (uint)f2bf(v1.z) | ((uint)f2bf(v1.w) << 16);
    }
    __syncthreads();

    bf16x8 a_frag[4];
#pragma unroll
    for (int bm = 0; bm < 4; ++bm) {
      int row = wr * 64 + bm * 16 + l16;
      a_frag[bm] = *(const bf16x8*)(&As[row * AS_STRIDE + quad * 8]);
    }
    bf16x8 b_frag[4];
#pragma unroll
    for (int bn = 0; bn < 4; ++bn) {
      int col = wc * 64 + bn * 16 + l16;
      bf16x8 bf;
#pragma unroll
      for (int j = 0; j < 8; ++j)
        bf[j] = (short)Bs[(quad * 8 + j) * BS_STRIDE + col];
      b_frag[bn] = bf;
    }
#pragma unroll
    for (int bm = 0; bm < 4; ++bm)
#pragma unroll
      for (int bn = 0; bn < 4; ++bn)
        acc[bm][bn] = __builtin_amdgcn_mfma_f32_16x16x32_bf16(
            a_frag[bm], b_frag[bn], acc[bm][bn], 0, 0, 0);
    __syncthreads();
  }

  // epilogue: C/D layout col=lane&15, row=quad*4+reg (m89-verified)
#pragma unroll
  for (int bm = 0; bm < 4; ++bm) {
    int rbase = m0 + wr * 64 + bm * 16 + quad * 4;
#pragma unroll
    for (int bn = 0; bn < 4; ++bn) {
      int col = n0 + wc * 64 + bn * 16 + l16;
#pragma unroll
      for (int i = 0; i < 4; ++i)
        C[(size_t)(rbase + i) * N + col] = f2bf(acc[bm][bn][i]);
    }
  }
}

// ---- Variant 2: A bf16, B fp32 -> C fp32 (the output projection) -------------
__global__ __launch_bounds__(256) void gemm_bf16f32_f32(
    const ushort* __restrict__ A, const float* __restrict__ B,
    float* __restrict__ C, int M, int N, int K)
{
  __shared__ __align__(16) ushort As[BM * AS_STRIDE];
  __shared__ __align__(16) ushort Bs[BKT * BS_STRIDE];

  const int tid  = threadIdx.x;
  const int lane = tid & 63;
  const int wave = tid >> 6;
  const int wr = wave >> 1, wc = wave & 1;
  const int m0 = blockIdx.y * BM;
  const int n0 = blockIdx.x * BN;
  const int quad = lane >> 4;
  const int l16  = lane & 15;

  f32x4 acc[4][4];
#pragma unroll
  for (int bm = 0; bm < 4; ++bm)
#pragma unroll
    for (int bn = 0; bn < 4; ++bn)
      acc[bm][bn] = (f32x4){0.f, 0.f, 0.f, 0.f};

  for (int k0 = 0; k0 < K; k0 += BKT) {
    // stage A tile 128x32 (already bf16): uint4 path
#pragma unroll
    for (int c = 0; c < 2; ++c) {
      int id = tid + c * 256;
      int row = id >> 2, colg = (id & 3) << 3;
      uint4 v = *(const uint4*)(A + (size_t)(m0 + row) * K + k0 + colg);
      *(uint4*)(&As[row * AS_STRIDE + colg]) = v;
    }
    // stage B tile 32x128 fp32 -> bf16
#pragma unroll
    for (int c = 0; c < 2; ++c) {
      int id = tid + c * 256;
      int row = id >> 4, colg = (id & 15) << 3;
      const float* src = B + (size_t)(k0 + row) * N + n0 + colg;
      float4 v0 = *(const float4*)src;
      float4 v1 = *(const float4*)(src + 4);
      uint* dst = (uint*)(&Bs[row * BS_STRIDE + colg]);
      dst[0] = (uint)f2bf(v0.x) | ((uint)f2bf(v0.y) << 16);
      dst[1] = (uint)f2bf(v0.z) | ((uint)f2bf(v0.w) << 16);
      dst[2] = (uint)f2bf(v1.x) | ((uint)f2bf(v1.y) << 16);
      dst[3] = (uint)f2bf(v1.z) | ((uint)f2bf(v1.w) << 16);
    }
    __syncthreads();

    bf16x8 a_frag[4];
#pragma unroll
    for (int bm = 0; bm < 4; ++bm) {
      int row = wr * 64 + bm * 16 + l16;
      a_frag[bm] = *(const bf16x8*)(&As[row * AS_STRIDE + quad * 8]);
    }
    bf16x8 b_frag[4];
#pragma unroll
    for (int bn = 0; bn < 4; ++bn) {
      int col = wc * 64 + bn * 16 + l16;
      bf16x8 bf;
#pragma unroll
      for (int j = 0; j < 8; ++j)
        bf[j] = (short)Bs[(quad * 8 + j) * BS_STRIDE + col];
      b_frag[bn] = bf;
    }
#pragma unroll
    for (int bm = 0; bm < 4; ++bm)
#pragma unroll
      for (int bn = 0; bn < 4; ++bn)
        acc[bm][bn] = __builtin_amdgcn_mfma_f32_16x16x32_bf16(
            a_frag[bm], b_frag[bn], acc[bm][bn], 0, 0, 0);
    __syncthreads();
  }

#pragma unroll
  for (int bm = 0; bm < 4; ++bm) {
    int rbase = m0 + wr * 64 + bm * 16 + quad * 4;
#pragma unroll
    for (int bn = 0; bn < 4; ++bn) {
      int col = n0 + wc * 64 + bn * 16 + l16;
#pragma unroll
      for (int i = 0; i < 4; ++i)
        C[(size_t)(rbase + i) * N + col] = acc[bm][bn][i];
    }
  }
}

// ---------------- RoPE (interleaved pairs), in place on bf16 ------------------
__global__ __launch_bounds__(256) void rope_kernel(
    ushort* __restrict__ t, const float* __restrict__ cosb,
    const float* __restrict__ sinb, int shift)
{
  int idx = blockIdx.x * 256 + threadIdx.x;   // pair index over S*H*64
  int p  = idx & 63;
  int sh = idx >> 6;          // s*H + h
  int s  = sh >> shift;       // shift = log2(H)
  uint* bp = (uint*)(t + ((size_t)sh << 7)) + p;
  uint u = *bp;
  float t1 = bflo(u), t2 = bfhi(u);
  float c  = cosb[(s << 6) + p];
  float sv = sinb[(s << 6) + p];
  float o1 = t1 * c - t2 * sv;
  float o2 = t1 * sv + t2 * c;
  *bp = ((uint)f2bf(o1)) | (((uint)f2bf(o2)) << 16);
}

// ---------------- Flash attention (vector fp32), BQ=32, BK=32 -----------------
// O may alias Q: each block reads exactly its own (q-tile, head) slice of Q
// into LDS at block start, and writes O to those same addresses at block end.
#define TSTRIDE 132   // ushorts per LDS row (264B: 8B-aligned rows)

__global__ __launch_bounds__(256) void attn_kernel(
    const ushort* __restrict__ Q, const ushort* __restrict__ K,
    const ushort* __restrict__ V, ushort* __restrict__ O)
{
  __shared__ __align__(16) ushort Qt[32][TSTRIDE];
  __shared__ __align__(16) ushort Kt[32][TSTRIDE];
  __shared__ __align__(16) ushort Vt[32][TSTRIDE];
  __shared__ float Ssc[32][33];
  __shared__ float mrow[32], lrow[32], arow[32];

  const int tid = threadIdx.x;
  const int h   = blockIdx.y;
  const int kvh = h >> 2;           // REPEATS = 4
  const int q0  = blockIdx.x * 32;
  const int qr  = tid >> 3;         // 0..31 (row within tile)
  const int g8  = tid & 7;          // 0..7
  const int cg  = g8 * 16;          // 16-col group for O / loads

  // load Q tile (32 x 128)
  {
    const ushort* src = Q + (size_t)(q0 + qr) * DIM + h * HD + cg;
    uint4 v0 = *(const uint4*)src;
    uint4 v1 = *(const uint4*)(src + 8);
    uint2* dst = (uint2*)&Qt[qr][cg];   // byte off = 264*qr + 2*cg ≡ 0 mod 8
    dst[0] = make_uint2(v0.x, v0.y); dst[1] = make_uint2(v0.z, v0.w);
    dst[2] = make_uint2(v1.x, v1.y); dst[3] = make_uint2(v1.z, v1.w);
  }
  if (tid < 32) { mrow[tid] = -1.0e30f; lrow[tid] = 0.f; }

  float o[16];
#pragma unroll
  for (int i = 0; i < 16; ++i) o[i] = 0.f;

  for (int kb = 0; kb < SEQ; kb += 32) {
    // stage K/V tiles (32 x 128 each)
    {
      const ushort* ksrc = K + (size_t)(kb + qr) * KVDIM + kvh * HD + cg;
      const ushort* vsrc = V + (size_t)(kb + qr) * KVDIM + kvh * HD + cg;
      uint4 a0 = *(const uint4*)ksrc;
      uint4 a1 = *(const uint4*)(ksrc + 8);
      uint4 b0 = *(const uint4*)vsrc;
      uint4 b1 = *(const uint4*)(vsrc + 8);
      uint2* kd = (uint2*)&Kt[qr][cg];
      kd[0] = make_uint2(a0.x, a0.y); kd[1] = make_uint2(a0.z, a0.w);
      kd[2] = make_uint2(a1.x, a1.y); kd[3] = make_uint2(a1.z, a1.w);
      uint2* vd = (uint2*)&Vt[qr][cg];
      vd[0] = make_uint2(b0.x, b0.y); vd[1] = make_uint2(b0.z, b0.w);
      vd[2] = make_uint2(b1.x, b1.y); vd[3] = make_uint2(b1.z, b1.w);
    }
    __syncthreads();

    // S[qr][kc..kc+3] = Q[qr] . K[kc..kc+3]
    float sacc[4] = {0.f, 0.f, 0.f, 0.f};
    const int kc = g8 * 4;
#pragma unroll 4
    for (int d = 0; d < HD; d += 4) {
      uint2 qv = *(const uint2*)&Qt[qr][d];
      float qa = bflo(qv.x), qb = bfhi(qv.x);
      float qc = bflo(qv.y), qd = bfhi(qv.y);
#pragma unroll
      for (int jj = 0; jj < 4; ++jj) {
        uint2 kv2 = *(const uint2*)&Kt[kc + jj][d];
        sacc[jj] += qa * bflo(kv2.x) + qb * bfhi(kv2.x)
                  + qc * bflo(kv2.y) + qd * bfhi(kv2.y);
      }
    }
#pragma unroll
    for (int jj = 0; jj < 4; ++jj) Ssc[qr][kc + jj] = sacc[jj] * SCALE;
    __syncthreads();

    // online softmax row update (one thread per row)
    if (tid < 32) {
      int r = tid;
      float m_old = mrow[r];
      float mx = m_old;
#pragma unroll
      for (int j = 0; j < 32; ++j) mx = fmaxf(mx, Ssc[r][j]);
      float alpha = __expf(m_old - mx);
      float l = lrow[r] * alpha;
#pragma unroll
      for (int j = 0; j < 32; ++j) {
        float pv = __expf(Ssc[r][j] - mx);
        Ssc[r][j] = pv;
        l += pv;
      }
      mrow[r] = mx; lrow[r] = l; arow[r] = alpha;
    }
    __syncthreads();

    // rescale + PV accumulate
    float alpha = arow[qr];
#pragma unroll
    for (int i = 0; i < 16; ++i) o[i] *= alpha;
#pragma unroll 4
    for (int j = 0; j < 32; ++j) {
      float p = Ssc[qr][j];
      uint2 v0 = *(const uint2*)&Vt[j][cg];
      uint2 v1 = *(const uint2*)&Vt[j][cg + 4];
      uint2 v2 = *(const uint2*)&Vt[j][cg + 8];
      uint2 v3 = *(const uint2*)&Vt[j][cg + 12];
      o[0]  += p * bflo(v0.x); o[1]  += p * bfhi(v0.x);
      o[2]  += p * bflo(v0.y); o[3]  += p * bfhi(v0.y);
      o[4]  += p * bflo(v1.x); o[5]  += p * bfhi(v1.x);
      o[6]  += p * bflo(v1.y); o[7]  += p * bfhi(v1.y);
      o[8]  += p * bflo(v2.x); o[9]  += p * bfhi(v2.x);
      o[10] += p * bflo(v2.y); o[11] += p * bfhi(v2.y);
      o[12] += p * bflo(v3.x); o[13] += p * bfhi(v3.x);
      o[14] += p * bflo(v3.y); o[15] += p * bfhi(v3.y);
    }
    __syncthreads();
  }

  float linv = 1.0f / lrow[qr];
  const size_t obase = (size_t)(q0 + qr) * DIM + h * HD + cg;
#pragma unroll
  for (int i = 0; i < 16; ++i) O[obase + i] = f2bf(o[i] * linv);
}

// ---------------- launcher ----------------------------------------------------
extern "C" void kernel_launch(void* const* d_in, const int* in_sizes, int n_in,
                              void* d_out, int out_size, void* d_ws, size_t ws_size,
                              hipStream_t stream) {
  // inputs are fp32 per the reference
  const float* x  = (const float*)d_in[0];
  const float* fc = (const float*)d_in[1];
  const float* fs = (const float*)d_in[2];
  const float* wq = (const float*)d_in[3];
  const float* wk = (const float*)d_in[4];
  const float* wv = (const float*)d_in[5];
  const float* wo = (const float*)d_in[6];
  float* out = (float*)d_out;

  // bf16 intermediates in ws: 25.2 MB total
  ushort* qb = (ushort*)d_ws;                    // 2048*4096 bf16 (16.8 MB)
  ushort* kb = qb + (size_t)SEQ * DIM;           // 2048*1024 bf16 (4.2 MB)
  ushort* vb = kb + (size_t)SEQ * KVDIM;         // 2048*1024 bf16 (4.2 MB)
  ushort* ab = qb;                               // attention out aliases Q (safe)

  dim3 blk(256);

  // projections (fp32 in -> bf16 out)
  gemm_f32f32_bf16<<<dim3(DIM / BN, SEQ / BM), blk, 0, stream>>>(x, wq, qb, SEQ, DIM, DIM);
  gemm_f32f32_bf16<<<dim3(KVDIM / BN, SEQ / BM), blk, 0, stream>>>(x, wk, kb, SEQ, KVDIM, DIM);
  gemm_f32f32_bf16<<<dim3(KVDIM / BN, SEQ / BM), blk, 0, stream>>>(x, wv, vb, SEQ, KVDIM, DIM);

  // rope on q (H=32 -> shift 5) and k (H=8 -> shift 3)
  rope_kernel<<<(SEQ * NH * 64) / 256, blk, 0, stream>>>(qb, fc, fs, 5);
  rope_kernel<<<(SEQ * NKV * 64) / 256, blk, 0, stream>>>(kb, fc, fs, 3);

  // attention (writes its output over its own Q slice)
  attn_kernel<<<dim3(SEQ / 32, NH), blk, 0, stream>>>(qb, kb, vb, ab);

  // output projection (bf16 A, fp32 B -> fp32 out)
  gemm_bf16f32_f32<<<dim3(DIM / BN, SEQ / BM), blk, 0, stream>>>(ab, wo, out, SEQ, DIM, DIM);
}

// Round 4
// 1088.338 us; speedup vs baseline: 2.4467x; 2.4467x over previous
//
#include <hip/hip_runtime.h>
#include <hip/hip_bf16.h>

#define SEQ   2048
#define DIM   4096
#define NH    32
#define NKV   8
#define HD    128
#define KVDIM 1024
#define SCALE 0.08838834764831845f

typedef __attribute__((ext_vector_type(8))) short bf16x8;
typedef __attribute__((ext_vector_type(4))) float f32x4;

__device__ __forceinline__ float bfhi(uint u) {
  union { uint i; float f; } v; v.i = u & 0xffff0000u; return v.f;
}
__device__ __forceinline__ float bflo(uint u) {
  union { uint i; float f; } v; v.i = u << 16; return v.f;
}
__device__ __forceinline__ ushort f2bf(float f) {  // RTN fp32 -> bf16 bits
  __hip_bfloat16 h = __float2bfloat16(f);
  return *reinterpret_cast<ushort*>(&h);
}

// ---------------- GEMM tiles: 128x128, BK=32, 4 waves (2x2), 16 MFMA/iter -----
#define BM 128
#define BN 128
#define BKT 32
#define AS_STRIDE 40    // ushorts; 80B rows -> 16B-aligned b128 LDS ops
#define BS_STRIDE 130   // ushorts; odd rows only 4B-aligned: 4B stores only

// ---- Variant 1: A fp32, B fp32 -> C bf16 (Q/K/V projections) -----------------
__global__ __launch_bounds__(256) void gemm_f32f32_bf16(
    const float* __restrict__ A, const float* __restrict__ B,
    ushort* __restrict__ C, int M, int N, int K)
{
  __shared__ __align__(16) ushort As[BM * AS_STRIDE];
  __shared__ __align__(16) ushort Bs[BKT * BS_STRIDE];

  const int tid  = threadIdx.x;
  const int lane = tid & 63;
  const int wave = tid >> 6;
  const int wr = wave >> 1, wc = wave & 1;
  const int m0 = blockIdx.y * BM;
  const int n0 = blockIdx.x * BN;
  const int quad = lane >> 4;
  const int l16  = lane & 15;

  f32x4 acc[4][4];
#pragma unroll
  for (int bm = 0; bm < 4; ++bm)
#pragma unroll
    for (int bn = 0; bn < 4; ++bn)
      acc[bm][bn] = (f32x4){0.f, 0.f, 0.f, 0.f};

  for (int k0 = 0; k0 < K; k0 += BKT) {
#pragma unroll
    for (int c = 0; c < 2; ++c) {
      int id = tid + c * 256;
      int row = id >> 2, colg = (id & 3) << 3;
      const float* src = A + (size_t)(m0 + row) * K + k0 + colg;
      float4 v0 = *(const float4*)src;
      float4 v1 = *(const float4*)(src + 4);
      ushort* dst = &As[row * AS_STRIDE + colg];
      dst[0] = f2bf(v0.x); dst[1] = f2bf(v0.y);
      dst[2] = f2bf(v0.z); dst[3] = f2bf(v0.w);
      dst[4] = f2bf(v1.x); dst[5] = f2bf(v1.y);
      dst[6] = f2bf(v1.z); dst[7] = f2bf(v1.w);
    }
#pragma unroll
    for (int c = 0; c < 2; ++c) {
      int id = tid + c * 256;
      int row = id >> 4, colg = (id & 15) << 3;
      const float* src = B + (size_t)(k0 + row) * N + n0 + colg;
      float4 v0 = *(const float4*)src;
      float4 v1 = *(const float4*)(src + 4);
      uint* dst = (uint*)(&Bs[row * BS_STRIDE + colg]);
      dst[0] = (uint)f2bf(v0.x) | ((uint)f2bf(v0.y) << 16);
      dst[1] = (uint)f2bf(v0.z) | ((uint)f2bf(v0.w) << 16);
      dst[2] = (uint)f2bf(v1.x) | ((uint)f2bf(v1.y) << 16);
      dst[3] = (uint)f2bf(v1.z) | ((uint)f2bf(v1.w) << 16);
    }
    __syncthreads();

    bf16x8 a_frag[4];
#pragma unroll
    for (int bm = 0; bm < 4; ++bm) {
      int row = wr * 64 + bm * 16 + l16;
      a_frag[bm] = *(const bf16x8*)(&As[row * AS_STRIDE + quad * 8]);
    }
    bf16x8 b_frag[4];
#pragma unroll
    for (int bn = 0; bn < 4; ++bn) {
      int col = wc * 64 + bn * 16 + l16;
      bf16x8 bf;
#pragma unroll
      for (int j = 0; j < 8; ++j)
        bf[j] = (short)Bs[(quad * 8 + j) * BS_STRIDE + col];
      b_frag[bn] = bf;
    }
#pragma unroll
    for (int bm = 0; bm < 4; ++bm)
#pragma unroll
      for (int bn = 0; bn < 4; ++bn)
        acc[bm][bn] = __builtin_amdgcn_mfma_f32_16x16x32_bf16(
            a_frag[bm], b_frag[bn], acc[bm][bn], 0, 0, 0);
    __syncthreads();
  }

#pragma unroll
  for (int bm = 0; bm < 4; ++bm) {
    int rbase = m0 + wr * 64 + bm * 16 + quad * 4;
#pragma unroll
    for (int bn = 0; bn < 4; ++bn) {
      int col = n0 + wc * 64 + bn * 16 + l16;
#pragma unroll
      for (int i = 0; i < 4; ++i)
        C[(size_t)(rbase + i) * N + col] = f2bf(acc[bm][bn][i]);
    }
  }
}

// ---- Variant 2: A bf16, B fp32 -> C fp32 (output projection) -----------------
__global__ __launch_bounds__(256) void gemm_bf16f32_f32(
    const ushort* __restrict__ A, const float* __restrict__ B,
    float* __restrict__ C, int M, int N, int K)
{
  __shared__ __align__(16) ushort As[BM * AS_STRIDE];
  __shared__ __align__(16) ushort Bs[BKT * BS_STRIDE];

  const int tid  = threadIdx.x;
  const int lane = tid & 63;
  const int wave = tid >> 6;
  const int wr = wave >> 1, wc = wave & 1;
  const int m0 = blockIdx.y * BM;
  const int n0 = blockIdx.x * BN;
  const int quad = lane >> 4;
  const int l16  = lane & 15;

  f32x4 acc[4][4];
#pragma unroll
  for (int bm = 0; bm < 4; ++bm)
#pragma unroll
    for (int bn = 0; bn < 4; ++bn)
      acc[bm][bn] = (f32x4){0.f, 0.f, 0.f, 0.f};

  for (int k0 = 0; k0 < K; k0 += BKT) {
#pragma unroll
    for (int c = 0; c < 2; ++c) {
      int id = tid + c * 256;
      int row = id >> 2, colg = (id & 3) << 3;
      uint4 v = *(const uint4*)(A + (size_t)(m0 + row) * K + k0 + colg);
      *(uint4*)(&As[row * AS_STRIDE + colg]) = v;
    }
#pragma unroll
    for (int c = 0; c < 2; ++c) {
      int id = tid + c * 256;
      int row = id >> 4, colg = (id & 15) << 3;
      const float* src = B + (size_t)(k0 + row) * N + n0 + colg;
      float4 v0 = *(const float4*)src;
      float4 v1 = *(const float4*)(src + 4);
      uint* dst = (uint*)(&Bs[row * BS_STRIDE + colg]);
      dst[0] = (uint)f2bf(v0.x) | ((uint)f2bf(v0.y) << 16);
      dst[1] = (uint)f2bf(v0.z) | ((uint)f2bf(v0.w) << 16);
      dst[2] = (uint)f2bf(v1.x) | ((uint)f2bf(v1.y) << 16);
      dst[3] = (uint)f2bf(v1.z) | ((uint)f2bf(v1.w) << 16);
    }
    __syncthreads();

    bf16x8 a_frag[4];
#pragma unroll
    for (int bm = 0; bm < 4; ++bm) {
      int row = wr * 64 + bm * 16 + l16;
      a_frag[bm] = *(const bf16x8*)(&As[row * AS_STRIDE + quad * 8]);
    }
    bf16x8 b_frag[4];
#pragma unroll
    for (int bn = 0; bn < 4; ++bn) {
      int col = wc * 64 + bn * 16 + l16;
      bf16x8 bf;
#pragma unroll
      for (int j = 0; j < 8; ++j)
        bf[j] = (short)Bs[(quad * 8 + j) * BS_STRIDE + col];
      b_frag[bn] = bf;
    }
#pragma unroll
    for (int bm = 0; bm < 4; ++bm)
#pragma unroll
      for (int bn = 0; bn < 4; ++bn)
        acc[bm][bn] = __builtin_amdgcn_mfma_f32_16x16x32_bf16(
            a_frag[bm], b_frag[bn], acc[bm][bn], 0, 0, 0);
    __syncthreads();
  }

#pragma unroll
  for (int bm = 0; bm < 4; ++bm) {
    int rbase = m0 + wr * 64 + bm * 16 + quad * 4;
#pragma unroll
    for (int bn = 0; bn < 4; ++bn) {
      int col = n0 + wc * 64 + bn * 16 + l16;
#pragma unroll
      for (int i = 0; i < 4; ++i)
        C[(size_t)(rbase + i) * N + col] = acc[bm][bn][i];
    }
  }
}

// ---------------- RoPE (interleaved pairs), in place on bf16 ------------------
__global__ __launch_bounds__(256) void rope_kernel(
    ushort* __restrict__ t, const float* __restrict__ cosb,
    const float* __restrict__ sinb, int shift)
{
  int idx = blockIdx.x * 256 + threadIdx.x;
  int p  = idx & 63;
  int sh = idx >> 6;
  int s  = sh >> shift;
  uint* bp = (uint*)(t + ((size_t)sh << 7)) + p;
  uint u = *bp;
  float t1 = bflo(u), t2 = bfhi(u);
  float c  = cosb[(s << 6) + p];
  float sv = sinb[(s << 6) + p];
  float o1 = t1 * c - t2 * sv;
  float o2 = t1 * sv + t2 * c;
  *bp = ((uint)f2bf(o1)) | (((uint)f2bf(o2)) << 16);
}

// ---------------- MFMA flash attention: BQ=64, BK=64, 4 waves -----------------
// Layouts (m89/m120-verified): A[m=l16][k=quad*8+j]; B[k=quad*8+j][n=l16];
// C/D: row=quad*4+reg, col=l16.
// Q-frags hoisted to regs; P round-trips LDS (C-layout -> A-layout), wave-local.
// V staged transposed so PV B-frags are contiguous ds_read_b128.
// O aliases Q: block reads Q only at start, writes same region at end.
#define BQA  64
#define BKA  64
#define KSTR 136   // Qs/Ks row stride (272 B: 16B-aligned, 68 banks = +4 mod 32)
#define PSTR 72    // Ps/Vt row stride (144 B: 16B-aligned, 36 banks = +4 mod 32)

__global__ __launch_bounds__(256) void attn_mfma(
    const ushort* __restrict__ Q, const ushort* __restrict__ K,
    const ushort* __restrict__ V, ushort* __restrict__ O)
{
  __shared__ __align__(16) ushort Ks[BKA * KSTR];   // 17408 B
  __shared__ __align__(16) ushort Vt[HD * PSTR];    // 18432 B (transposed V)
  __shared__ __align__(16) ushort QP[BQA * KSTR];   // 17408 B (Q, then P)

  const int tid  = threadIdx.x;
  const int lane = tid & 63;
  const int w    = tid >> 6;       // wave 0..3 -> q-rows w*16..+15
  const int l16  = lane & 15;
  const int quad = lane >> 4;
  const int h    = blockIdx.y;
  const int kvh  = h >> 2;         // REPEATS = 4
  const int q0   = blockIdx.x * BQA;

  // stage Q tile (64 x 128)
  {
    int row = tid >> 2, colg = (tid & 3) * 32;
    const ushort* src = Q + (size_t)(q0 + row) * DIM + h * HD + colg;
    ushort* dst = &QP[row * KSTR + colg];
#pragma unroll
    for (int i = 0; i < 4; ++i)
      *(uint4*)(dst + i * 8) = *(const uint4*)(src + i * 8);
  }
  __syncthreads();

  // hoist Q A-frags: rows w*16+l16, k = ks*32 + quad*8 + j
  bf16x8 qf[4];
#pragma unroll
  for (int ks = 0; ks < 4; ++ks)
    qf[ks] = *(const bf16x8*)(&QP[(w * 16 + l16) * KSTR + ks * 32 + quad * 8]);

  f32x4 oacc[8];
#pragma unroll
  for (int i = 0; i < 8; ++i) oacc[i] = (f32x4){0.f, 0.f, 0.f, 0.f};
  float mrow[4] = {-1e30f, -1e30f, -1e30f, -1e30f};
  float lrow[4] = {0.f, 0.f, 0.f, 0.f};

  for (int kb = 0; kb < SEQ; kb += BKA) {
    __syncthreads();   // prior iter's LDS reads (and q-frag reads) drained
    // stage K tile straight (64 x 128)
    {
      int row = tid >> 2, colg = (tid & 3) * 32;
      const ushort* src = K + (size_t)(kb + row) * KVDIM + kvh * HD + colg;
      ushort* dst = &Ks[row * KSTR + colg];
#pragma unroll
      for (int i = 0; i < 4; ++i)
        *(uint4*)(dst + i * 8) = *(const uint4*)(src + i * 8);
    }
    // stage V transposed: Vt[n][k], scalar writes (2 lanes/bank: free)
    {
      int krow = tid & 63, ng = tid >> 6;
      const ushort* src = V + (size_t)(kb + krow) * KVDIM + kvh * HD + ng * 32;
#pragma unroll
      for (int i = 0; i < 4; ++i) {
        uint4 vv = *(const uint4*)(src + i * 8);
        ushort e[8];
        *(uint4*)e = vv;
#pragma unroll
        for (int jj = 0; jj < 8; ++jj)
          Vt[(ng * 32 + i * 8 + jj) * PSTR + krow] = e[jj];
      }
    }
    __syncthreads();

    // S = Q . K^T  (B-frag of K^T == A-style contiguous read of K rows)
    f32x4 sacc[4];
#pragma unroll
    for (int bn = 0; bn < 4; ++bn) sacc[bn] = (f32x4){0.f, 0.f, 0.f, 0.f};
#pragma unroll
    for (int bn = 0; bn < 4; ++bn)
#pragma unroll
      for (int ks = 0; ks < 4; ++ks) {
        bf16x8 kf = *(const bf16x8*)(&Ks[(bn * 16 + l16) * KSTR + ks * 32 + quad * 8]);
        sacc[bn] = __builtin_amdgcn_mfma_f32_16x16x32_bf16(qf[ks], kf, sacc[bn], 0, 0, 0);
      }

    // online softmax per reg-row r; row data spread over 16 l16-lanes in quad
    float p[4][4];     // [bn][r]
    float alpha[4];
#pragma unroll
    for (int r = 0; r < 4; ++r) {
      float s0 = sacc[0][r] * SCALE, s1 = sacc[1][r] * SCALE;
      float s2 = sacc[2][r] * SCALE, s3 = sacc[3][r] * SCALE;
      float lm = fmaxf(fmaxf(s0, s1), fmaxf(s2, s3));
#pragma unroll
      for (int off = 1; off < 16; off <<= 1)
        lm = fmaxf(lm, __shfl_xor(lm, off));
      float mn = fmaxf(mrow[r], lm);
      alpha[r] = __expf(mrow[r] - mn);
      mrow[r] = mn;
      float p0 = __expf(s0 - mn), p1 = __expf(s1 - mn);
      float p2 = __expf(s2 - mn), p3 = __expf(s3 - mn);
      p[0][r] = p0; p[1][r] = p1; p[2][r] = p2; p[3][r] = p3;
      float ls = p0 + p1 + p2 + p3;
#pragma unroll
      for (int off = 1; off < 16; off <<= 1)
        ls += __shfl_xor(ls, off);
      lrow[r] = lrow[r] * alpha[r] + ls;
    }
#pragma unroll
    for (int nt = 0; nt < 8; ++nt)
#pragma unroll
      for (int r = 0; r < 4; ++r) oacc[nt][r] *= alpha[r];

    // write P (C-layout) to wave-local LDS rows; read back in A-layout.
    // Only wave w touches rows w*16..w*16+15 -> lgkmcnt ordering suffices.
#pragma unroll
    for (int bn = 0; bn < 4; ++bn)
#pragma unroll
      for (int r = 0; r < 4; ++r)
        QP[(w * 16 + quad * 4 + r) * PSTR + bn * 16 + l16] = f2bf(p[bn][r]);

    // PV
#pragma unroll
    for (int kk = 0; kk < 2; ++kk) {
      bf16x8 pf = *(const bf16x8*)(&QP[(w * 16 + l16) * PSTR + kk * 32 + quad * 8]);
#pragma unroll
      for (int nt = 0; nt < 8; ++nt) {
        bf16x8 vf = *(const bf16x8*)(&Vt[(nt * 16 + l16) * PSTR + kk * 32 + quad * 8]);
        oacc[nt] = __builtin_amdgcn_mfma_f32_16x16x32_bf16(pf, vf, oacc[nt], 0, 0, 0);
      }
    }
  }

  // epilogue: O[row][col], row=q0+w*16+quad*4+r, col=h*HD+nt*16+l16
  float linv[4];
#pragma unroll
  for (int r = 0; r < 4; ++r) linv[r] = 1.0f / lrow[r];
#pragma unroll
  for (int nt = 0; nt < 8; ++nt)
#pragma unroll
    for (int r = 0; r < 4; ++r) {
      int grow = q0 + w * 16 + quad * 4 + r;
      int gcol = h * HD + nt * 16 + l16;
      O[(size_t)grow * DIM + gcol] = f2bf(oacc[nt][r] * linv[r]);
    }
}

// ---------------- launcher ----------------------------------------------------
extern "C" void kernel_launch(void* const* d_in, const int* in_sizes, int n_in,
                              void* d_out, int out_size, void* d_ws, size_t ws_size,
                              hipStream_t stream) {
  const float* x  = (const float*)d_in[0];
  const float* fc = (const float*)d_in[1];
  const float* fs = (const float*)d_in[2];
  const float* wq = (const float*)d_in[3];
  const float* wk = (const float*)d_in[4];
  const float* wv = (const float*)d_in[5];
  const float* wo = (const float*)d_in[6];
  float* out = (float*)d_out;

  ushort* qb = (ushort*)d_ws;                    // 2048*4096 bf16
  ushort* kb = qb + (size_t)SEQ * DIM;           // 2048*1024 bf16
  ushort* vb = kb + (size_t)SEQ * KVDIM;         // 2048*1024 bf16
  ushort* ab = qb;                               // attention out aliases Q

  dim3 blk(256);

  gemm_f32f32_bf16<<<dim3(DIM / BN, SEQ / BM), blk, 0, stream>>>(x, wq, qb, SEQ, DIM, DIM);
  gemm_f32f32_bf16<<<dim3(KVDIM / BN, SEQ / BM), blk, 0, stream>>>(x, wk, kb, SEQ, KVDIM, DIM);
  gemm_f32f32_bf16<<<dim3(KVDIM / BN, SEQ / BM), blk, 0, stream>>>(x, wv, vb, SEQ, KVDIM, DIM);

  rope_kernel<<<(SEQ * NH * 64) / 256, blk, 0, stream>>>(qb, fc, fs, 5);
  rope_kernel<<<(SEQ * NKV * 64) / 256, blk, 0, stream>>>(kb, fc, fs, 3);

  attn_mfma<<<dim3(SEQ / BQA, NH), blk, 0, stream>>>(qb, kb, vb, ab);

  gemm_bf16f32_f32<<<dim3(DIM / BN, SEQ / BM), blk, 0, stream>>>(ab, wo, out, SEQ, DIM, DIM);
}

// Round 5
// 686.118 us; speedup vs baseline: 3.8811x; 1.5862x over previous
//
#include <hip/hip_runtime.h>
#include <hip/hip_bf16.h>

#define SEQ   2048
#define DIM   4096
#define NH    32
#define NKV   8
#define HD    128
#define KVDIM 1024
#define SCALE 0.08838834764831845f

typedef __attribute__((ext_vector_type(8))) short bf16x8;
typedef __attribute__((ext_vector_type(4))) float f32x4;

__device__ __forceinline__ ushort f2bf(float f) {  // RTN fp32 -> bf16 bits
  __hip_bfloat16 h = __float2bfloat16(f);
  return *reinterpret_cast<ushort*>(&h);
}

// async global->LDS, 16B per lane; LDS dest = wave-uniform base + lane*16
typedef const __attribute__((address_space(1))) uint* gas_ptr;
typedef __attribute__((address_space(3))) uint* las_ptr;
__device__ __forceinline__ void async16(const ushort* g, ushort* l) {
  __builtin_amdgcn_global_load_lds((gas_ptr)g, (las_ptr)l, 16, 0, 0);
}

// ---------------- fp32 -> bf16 elementwise (x) --------------------------------
__global__ __launch_bounds__(256) void convert_f32_bf16(
    const float* __restrict__ in, ushort* __restrict__ out)
{
  int i = (blockIdx.x * 256 + threadIdx.x) * 8;
  float4 a = *(const float4*)(in + i);
  float4 b = *(const float4*)(in + i + 4);
  uint4 u;
  u.x = (uint)f2bf(a.x) | ((uint)f2bf(a.y) << 16);
  u.y = (uint)f2bf(a.z) | ((uint)f2bf(a.w) << 16);
  u.z = (uint)f2bf(b.x) | ((uint)f2bf(b.y) << 16);
  u.w = (uint)f2bf(b.z) | ((uint)f2bf(b.w) << 16);
  *(uint4*)(out + i) = u;
}

// ---------------- W[K][N] fp32 -> WT[N][K] bf16 (32x32 LDS tiles) -------------
__global__ __launch_bounds__(256) void transpose_w(
    const float* __restrict__ W, ushort* __restrict__ WT, int K, int N)
{
  __shared__ float t[32][33];
  const int k0 = blockIdx.y * 32, n0 = blockIdx.x * 32;
  const int tid = threadIdx.x;
  {
    int r = tid >> 3, c0 = (tid & 7) * 4;
    float4 v = *(const float4*)(W + (size_t)(k0 + r) * N + n0 + c0);
    t[r][c0] = v.x; t[r][c0 + 1] = v.y; t[r][c0 + 2] = v.z; t[r][c0 + 3] = v.w;
  }
  __syncthreads();
  {
    int n = tid >> 3, kc = (tid & 7) * 4;
    ushort4 u;
    u.x = f2bf(t[kc + 0][n]); u.y = f2bf(t[kc + 1][n]);
    u.z = f2bf(t[kc + 2][n]); u.w = f2bf(t[kc + 3][n]);
    *(ushort4*)(WT + (size_t)(n0 + n) * K + k0 + kc) = u;
  }
}

// ---------------- m97-style GEMM: C = A[MxK] * BT[NxK]^T, bf16 ----------------
// 128x128 tile, BK=32, 4 waves 2x2, unpadded LDS, global_load_lds staging.
// mode 0: bf16 C natural (stride N). mode 1: fp32 C natural (stride N).
// mode 2: KV fused: n0<1024 -> bf16 C natural (stride KVDIM);
//         n0>=1024 -> bf16 C2 transposed: C2[(col-1024)*SEQ + m] (V^T).
__global__ __launch_bounds__(256) void gemm_bt(
    const ushort* __restrict__ A, const ushort* __restrict__ BT,
    void* __restrict__ Cv, void* __restrict__ C2v,
    int M, int N, int K, int mode)
{
  __shared__ __align__(16) ushort As[128 * 32];
  __shared__ __align__(16) ushort Bs[128 * 32];

  const int tid  = threadIdx.x;
  const int lane = tid & 63;
  const int w    = tid >> 6;
  const int wr = w >> 1, wc = w & 1;
  const int quad = lane >> 4, l16 = lane & 15;
  const int m0 = blockIdx.y * 128, n0 = blockIdx.x * 128;
  const int srow = lane >> 2;          // 0..15 row within 16-row chunk
  const int scol = (lane & 3) * 8;     // 0,8,16,24

  f32x4 acc[4][4];
#pragma unroll
  for (int bm = 0; bm < 4; ++bm)
#pragma unroll
    for (int bn = 0; bn < 4; ++bn)
      acc[bm][bn] = (f32x4){0.f, 0.f, 0.f, 0.f};

  for (int k0 = 0; k0 < K; k0 += 32) {
#pragma unroll
    for (int j = 0; j < 2; ++j) {
      const int rb = w * 32 + j * 16;  // wave-uniform
      async16(A  + (size_t)(m0 + rb + srow) * K + k0 + scol, &As[rb * 32]);
      async16(BT + (size_t)(n0 + rb + srow) * K + k0 + scol, &Bs[rb * 32]);
    }
    __syncthreads();   // drains vmcnt(0): staging complete

    bf16x8 af[4], bf[4];
#pragma unroll
    for (int bm = 0; bm < 4; ++bm)
      af[bm] = *(const bf16x8*)&As[(wr * 64 + bm * 16 + l16) * 32 + quad * 8];
#pragma unroll
    for (int bn = 0; bn < 4; ++bn)
      bf[bn] = *(const bf16x8*)&Bs[(wc * 64 + bn * 16 + l16) * 32 + quad * 8];
#pragma unroll
    for (int bm = 0; bm < 4; ++bm)
#pragma unroll
      for (int bn = 0; bn < 4; ++bn)
        acc[bm][bn] = __builtin_amdgcn_mfma_f32_16x16x32_bf16(
            af[bm], bf[bn], acc[bm][bn], 0, 0, 0);
    __syncthreads();
  }

  // C/D layout: row = quad*4 + i, col = l16 (m89-verified)
  if (mode == 0) {
    ushort* C = (ushort*)Cv;
#pragma unroll
    for (int bm = 0; bm < 4; ++bm) {
      int rbase = m0 + wr * 64 + bm * 16 + quad * 4;
#pragma unroll
      for (int bn = 0; bn < 4; ++bn) {
        int col = n0 + wc * 64 + bn * 16 + l16;
#pragma unroll
        for (int i = 0; i < 4; ++i)
          C[(size_t)(rbase + i) * N + col] = f2bf(acc[bm][bn][i]);
      }
    }
  } else if (mode == 1) {
    float* C = (float*)Cv;
#pragma unroll
    for (int bm = 0; bm < 4; ++bm) {
      int rbase = m0 + wr * 64 + bm * 16 + quad * 4;
#pragma unroll
      for (int bn = 0; bn < 4; ++bn) {
        int col = n0 + wc * 64 + bn * 16 + l16;
#pragma unroll
        for (int i = 0; i < 4; ++i)
          C[(size_t)(rbase + i) * N + col] = acc[bm][bn][i];
      }
    }
  } else {  // mode 2: KV fused
    if (n0 < 1024) {
      ushort* C = (ushort*)Cv;   // kb natural, stride KVDIM
#pragma unroll
      for (int bm = 0; bm < 4; ++bm) {
        int rbase = m0 + wr * 64 + bm * 16 + quad * 4;
#pragma unroll
        for (int bn = 0; bn < 4; ++bn) {
          int col = n0 + wc * 64 + bn * 16 + l16;
#pragma unroll
          for (int i = 0; i < 4; ++i)
            C[(size_t)(rbase + i) * KVDIM + col] = f2bf(acc[bm][bn][i]);
        }
      }
    } else {
      ushort* C2 = (ushort*)C2v; // V^T: C2[(col-1024)*SEQ + m], 4 m contiguous
#pragma unroll
      for (int bm = 0; bm < 4; ++bm) {
        int rbase = m0 + wr * 64 + bm * 16 + quad * 4;
#pragma unroll
        for (int bn = 0; bn < 4; ++bn) {
          int col = n0 + wc * 64 + bn * 16 + l16 - 1024;
          ushort4 u;
          u.x = f2bf(acc[bm][bn][0]); u.y = f2bf(acc[bm][bn][1]);
          u.z = f2bf(acc[bm][bn][2]); u.w = f2bf(acc[bm][bn][3]);
          *(ushort4*)(C2 + (size_t)col * SEQ + rbase) = u;
        }
      }
    }
  }
}

// ---------------- RoPE (interleaved pairs), in place on bf16 ------------------
__device__ __forceinline__ float bfhi(uint u) {
  union { uint i; float f; } v; v.i = u & 0xffff0000u; return v.f;
}
__device__ __forceinline__ float bflo(uint u) {
  union { uint i; float f; } v; v.i = u << 16; return v.f;
}
__global__ __launch_bounds__(256) void rope_kernel(
    ushort* __restrict__ t, const float* __restrict__ cosb,
    const float* __restrict__ sinb, int shift)
{
  int idx = blockIdx.x * 256 + threadIdx.x;
  int p  = idx & 63;
  int sh = idx >> 6;
  int s  = sh >> shift;
  uint* bp = (uint*)(t + ((size_t)sh << 7)) + p;
  uint u = *bp;
  float t1 = bflo(u), t2 = bfhi(u);
  float c  = cosb[(s << 6) + p];
  float sv = sinb[(s << 6) + p];
  float o1 = t1 * c - t2 * sv;
  float o2 = t1 * sv + t2 * c;
  *bp = ((uint)f2bf(o1)) | (((uint)f2bf(o2)) << 16);
}

// ---------------- MFMA flash attention: BQ=128, BK=64, 4 waves ----------------
// Each wave owns 32 q-rows (2 strips of 16). V pre-transposed globally (VT).
// LDS union: Q-phase uses [0..17408); loop: Ks | Vt | P. O aliases Q (safe).
#define KSTR 136   // 272 B rows (16B-aligned; l16-stride banks +4 mod 32)
#define PSTR 72    // 144 B rows
#define OFF_VT (64 * KSTR)              // 8704 ushorts
#define OFF_P  (64 * KSTR + 128 * PSTR) // 17920 ushorts

__global__ __launch_bounds__(256) void attn_mfma2(
    const ushort* __restrict__ Q, const ushort* __restrict__ K,
    const ushort* __restrict__ VT, ushort* __restrict__ O)
{
  __shared__ __align__(16) ushort SM[64 * KSTR + 2 * 128 * PSTR];  // 54272 B

  const int tid = threadIdx.x, lane = tid & 63, w = tid >> 6;
  const int l16 = lane & 15, quad = lane >> 4;
  const int h = blockIdx.y, kvh = h >> 2;
  const int q0 = blockIdx.x * 128;

  // stage Q tile (128 x 128) at SM[0], stride KSTR
  {
    int row = tid >> 1, half = tid & 1;
    const ushort* src = Q + (size_t)(q0 + row) * DIM + h * HD + half * 64;
    ushort* dst = &SM[row * KSTR + half * 64];
#pragma unroll
    for (int i = 0; i < 8; ++i)
      *(uint4*)(dst + i * 8) = *(const uint4*)(src + i * 8);
  }
  __syncthreads();

  bf16x8 qf[2][4];
#pragma unroll
  for (int st = 0; st < 2; ++st)
#pragma unroll
    for (int ks = 0; ks < 4; ++ks)
      qf[st][ks] = *(const bf16x8*)&SM[(w * 32 + st * 16 + l16) * KSTR + ks * 32 + quad * 8];

  f32x4 oacc[2][8];
#pragma unroll
  for (int st = 0; st < 2; ++st)
#pragma unroll
    for (int nt = 0; nt < 8; ++nt) oacc[st][nt] = (f32x4){0.f, 0.f, 0.f, 0.f};
  float m_i[2][4], l_i[2][4];
#pragma unroll
  for (int st = 0; st < 2; ++st)
#pragma unroll
    for (int r = 0; r < 4; ++r) { m_i[st][r] = -1e30f; l_i[st][r] = 0.f; }

  for (int kb = 0; kb < SEQ; kb += 64) {
    __syncthreads();   // prior iter's LDS reads (or Q-hoist) drained
    // stage K tile (64 x 128) at SM[0], stride KSTR
    {
      int row = tid >> 2, cg = (tid & 3) * 32;
      const ushort* src = K + (size_t)(kb + row) * KVDIM + kvh * HD + cg;
      ushort* dst = &SM[row * KSTR + cg];
#pragma unroll
      for (int i = 0; i < 4; ++i)
        *(uint4*)(dst + i * 8) = *(const uint4*)(src + i * 8);
    }
    // stage V^T tile (128 d-rows x 64 kv-cols) at OFF_VT, stride PSTR
    {
      int n = tid >> 1, half = tid & 1;
      const ushort* src = VT + (size_t)(kvh * 128 + n) * SEQ + kb + half * 32;
      ushort* dst = &SM[OFF_VT + n * PSTR + half * 32];
#pragma unroll
      for (int i = 0; i < 4; ++i)
        *(uint4*)(dst + i * 8) = *(const uint4*)(src + i * 8);
    }
    __syncthreads();

    // S = Q K^T : 32 MFMA
    f32x4 sacc[2][4];
#pragma unroll
    for (int st = 0; st < 2; ++st)
#pragma unroll
      for (int bn = 0; bn < 4; ++bn) sacc[st][bn] = (f32x4){0.f, 0.f, 0.f, 0.f};
#pragma unroll
    for (int bn = 0; bn < 4; ++bn)
#pragma unroll
      for (int ks = 0; ks < 4; ++ks) {
        bf16x8 kf = *(const bf16x8*)&SM[(bn * 16 + l16) * KSTR + ks * 32 + quad * 8];
        sacc[0][bn] = __builtin_amdgcn_mfma_f32_16x16x32_bf16(qf[0][ks], kf, sacc[0][bn], 0, 0, 0);
        sacc[1][bn] = __builtin_amdgcn_mfma_f32_16x16x32_bf16(qf[1][ks], kf, sacc[1][bn], 0, 0, 0);
      }

    // online softmax per strip/reg-row; row spread over 16 l16-lanes
    float alpha[2][4];
#pragma unroll
    for (int st = 0; st < 2; ++st)
#pragma unroll
      for (int r = 0; r < 4; ++r) {
        float s0 = sacc[st][0][r] * SCALE, s1 = sacc[st][1][r] * SCALE;
        float s2 = sacc[st][2][r] * SCALE, s3 = sacc[st][3][r] * SCALE;
        float lm = fmaxf(fmaxf(s0, s1), fmaxf(s2, s3));
#pragma unroll
        for (int off = 1; off < 16; off <<= 1) lm = fmaxf(lm, __shfl_xor(lm, off));
        float mn = fmaxf(m_i[st][r], lm);
        float a = __expf(m_i[st][r] - mn);
        m_i[st][r] = mn; alpha[st][r] = a;
        float p0 = __expf(s0 - mn), p1 = __expf(s1 - mn);
        float p2 = __expf(s2 - mn), p3 = __expf(s3 - mn);
        float ls = p0 + p1 + p2 + p3;
#pragma unroll
        for (int off = 1; off < 16; off <<= 1) ls += __shfl_xor(ls, off);
        l_i[st][r] = l_i[st][r] * a + ls;
        int prow = w * 32 + st * 16 + quad * 4 + r;   // wave-local P rows
        SM[OFF_P + prow * PSTR +  0 + l16] = f2bf(p0);
        SM[OFF_P + prow * PSTR + 16 + l16] = f2bf(p1);
        SM[OFF_P + prow * PSTR + 32 + l16] = f2bf(p2);
        SM[OFF_P + prow * PSTR + 48 + l16] = f2bf(p3);
      }
#pragma unroll
    for (int st = 0; st < 2; ++st)
#pragma unroll
      for (int nt = 0; nt < 8; ++nt)
#pragma unroll
        for (int r = 0; r < 4; ++r) oacc[st][nt][r] *= alpha[st][r];

    // PV : 32 MFMA (P wave-local; lgkmcnt orders write->read within wave)
#pragma unroll
    for (int kk = 0; kk < 2; ++kk) {
      bf16x8 pf0 = *(const bf16x8*)&SM[OFF_P + (w * 32 + l16) * PSTR + kk * 32 + quad * 8];
      bf16x8 pf1 = *(const bf16x8*)&SM[OFF_P + (w * 32 + 16 + l16) * PSTR + kk * 32 + quad * 8];
#pragma unroll
      for (int nt = 0; nt < 8; ++nt) {
        bf16x8 vf = *(const bf16x8*)&SM[OFF_VT + (nt * 16 + l16) * PSTR + kk * 32 + quad * 8];
        oacc[0][nt] = __builtin_amdgcn_mfma_f32_16x16x32_bf16(pf0, vf, oacc[0][nt], 0, 0, 0);
        oacc[1][nt] = __builtin_amdgcn_mfma_f32_16x16x32_bf16(pf1, vf, oacc[1][nt], 0, 0, 0);
      }
    }
  }

#pragma unroll
  for (int st = 0; st < 2; ++st)
#pragma unroll
    for (int r = 0; r < 4; ++r) {
      float linv = 1.0f / l_i[st][r];
      int grow = q0 + w * 32 + st * 16 + quad * 4 + r;
#pragma unroll
      for (int nt = 0; nt < 8; ++nt)
        O[(size_t)grow * DIM + h * HD + nt * 16 + l16] = f2bf(oacc[st][nt][r] * linv);
    }
}

// ---------------- launcher ----------------------------------------------------
extern "C" void kernel_launch(void* const* d_in, const int* in_sizes, int n_in,
                              void* d_out, int out_size, void* d_ws, size_t ws_size,
                              hipStream_t stream) {
  const float* x  = (const float*)d_in[0];
  const float* fc = (const float*)d_in[1];
  const float* fs = (const float*)d_in[2];
  const float* wq = (const float*)d_in[3];
  const float* wk = (const float*)d_in[4];
  const float* wv = (const float*)d_in[5];
  const float* wo = (const float*)d_in[6];
  float* out = (float*)d_out;

  // ws (bf16 elems): xb | wT (wqT then woT) | wkvT | qb | kb | vT  = 92.4 MB
  ushort* xb   = (ushort*)d_ws;
  ushort* wT   = xb   + (size_t)SEQ * DIM;      // 4096x4096
  ushort* wkvT = wT   + (size_t)DIM * DIM;      // 2048x4096
  ushort* qb   = wkvT + (size_t)2048 * DIM;
  ushort* kb   = qb   + (size_t)SEQ * DIM;
  ushort* vT   = kb   + (size_t)SEQ * KVDIM;    // 1024 x 2048
  ushort* ab   = qb;                            // attention out aliases Q

  dim3 blk(256);

  convert_f32_bf16<<<(SEQ * DIM) / 2048, blk, 0, stream>>>(x, xb);
  transpose_w<<<dim3(DIM / 32, DIM / 32), blk, 0, stream>>>(wq, wT, DIM, DIM);
  transpose_w<<<dim3(KVDIM / 32, DIM / 32), blk, 0, stream>>>(wk, wkvT, DIM, KVDIM);
  transpose_w<<<dim3(KVDIM / 32, DIM / 32), blk, 0, stream>>>(wv, wkvT + (size_t)KVDIM * DIM, DIM, KVDIM);

  // Q projection
  gemm_bt<<<dim3(DIM / 128, SEQ / 128), blk, 0, stream>>>(xb, wT, qb, nullptr, SEQ, DIM, DIM, 0);
  // fused K/V projection (K natural -> kb, V transposed -> vT)
  gemm_bt<<<dim3(2048 / 128, SEQ / 128), blk, 0, stream>>>(xb, wkvT, kb, vT, SEQ, 2048, DIM, 2);

  rope_kernel<<<(SEQ * NH * 64) / 256, blk, 0, stream>>>(qb, fc, fs, 5);
  rope_kernel<<<(SEQ * NKV * 64) / 256, blk, 0, stream>>>(kb, fc, fs, 3);

  attn_mfma2<<<dim3(SEQ / 128, NH), blk, 0, stream>>>(qb, kb, vT, ab);

  // transpose wo into the (now dead) wqT region, then output projection
  transpose_w<<<dim3(DIM / 32, DIM / 32), blk, 0, stream>>>(wo, wT, DIM, DIM);
  gemm_bt<<<dim3(DIM / 128, SEQ / 128), blk, 0, stream>>>(ab, wT, out, nullptr, SEQ, DIM, DIM, 1);
}